// Round 12
// baseline (301.175 us; speedup 1.0000x reference)
//
#include <hip/hip_runtime.h>
#include <hip/hip_bf16.h>
#include <stdint.h>

#define T_SEQ 2048
#define HS    2048
#define NH    16
#define DH    128
#define QKVN  (3*HS)

typedef __attribute__((ext_vector_type(8))) short          bf16x8;
typedef __attribute__((ext_vector_type(4))) float          f32x4;
typedef __attribute__((ext_vector_type(4))) unsigned short us4;
typedef __attribute__((ext_vector_type(8))) unsigned short us8;

// round-to-nearest-even f32 -> bf16 bits
__device__ __forceinline__ unsigned short f2bf(float x) {
  unsigned int u = __float_as_uint(x);
  return (unsigned short)((u + 0x7fffu + ((u >> 16) & 1u)) >> 16);
}

// async global->LDS, 16B per lane; lds base must be wave-uniform (lane i lands at base + i*16B)
__device__ __forceinline__ void gl_lds16(const void* g, void* l) {
  __builtin_amdgcn_global_load_lds((__attribute__((address_space(1))) void*)g,
                                   (__attribute__((address_space(3))) void*)l, 16, 0, 0);
}

// ---------------- elementwise cast f32 -> bf16 (vectorized 8/thread) ----------------
__global__ __launch_bounds__(256) void cast_bf16_kernel(const float* __restrict__ in,
                                                        unsigned short* __restrict__ out, int n) {
  int i = (blockIdx.x * 256 + threadIdx.x) * 8;
  if (i >= n) return;
  f32x4 a = *(const f32x4*)(in + i);
  f32x4 b = *(const f32x4*)(in + i + 4);
  us8 r;
#pragma unroll
  for (int j = 0; j < 4; ++j) { r[j] = f2bf(a[j]); r[j + 4] = f2bf(b[j]); }
  *(us8*)(out + i) = r;
}

// ---------------- RoPE cos/sin table [T][64] ----------------
__global__ __launch_bounds__(256) void rope_table_kernel(float* __restrict__ cosd,
                                                         float* __restrict__ sind) {
  int i = blockIdx.x * 256 + threadIdx.x;   // over T*64
  if (i >= T_SEQ * 64) return;
  int t = i >> 6, f = i & 63;
  float inv = expf(-9.210340371976184f * (float)f * (1.0f / 64.0f));
  float ang = (float)t * inv;
  float s, c;
  sincosf(ang, &s, &c);
  cosd[i] = c; sind[i] = s;
}

// ---------------- GEMM C[M][N] = A[M][K](bf16) * Bt[N][K](bf16)^T (+bias) ----------------
template <int BIAS, int BN>
__global__ __launch_bounds__(256, 4)
void gemm_bt(const unsigned short* __restrict__ A, const unsigned short* __restrict__ Bt,
             float* __restrict__ C, const float* __restrict__ bias, int M, int N, int K) {
  constexpr int FN = BN / 32;          // n-fragments per wave (128->4, 64->2)
  __shared__ unsigned short As[128 * 64];
  __shared__ unsigned short Bs[BN * 64];
  const int tid  = threadIdx.x;
  const int lane = tid & 63;
  const int w    = tid >> 6;
  const int fr   = lane & 15;   // fragment row/col
  const int fq   = lane >> 4;   // k-group
  const int bm   = blockIdx.y * 128;
  const int bn   = blockIdx.x * BN;
  const int wr   = (w >> 1) * 64;
  const int wc   = (w & 1) * (BN / 2);

  f32x4 acc[4][FN];
#pragma unroll
  for (int m = 0; m < 4; ++m)
#pragma unroll
    for (int n = 0; n < FN; ++n) { acc[m][n][0]=0.f; acc[m][n][1]=0.f; acc[m][n][2]=0.f; acc[m][n][3]=0.f; }

  const int srow = lane >> 3;
  const int sg   = (lane & 7) ^ srow;
  const unsigned short* Ag = A + (long)bm * K;
  const unsigned short* Bg = Bt + (long)bn * K;

  const int nk = K >> 6;
  for (int kt = 0; kt < nk; ++kt) {
    const int k0 = kt << 6;
    __syncthreads();               // previous compute done, LDS free
#pragma unroll
    for (int i = 0; i < 4; ++i) {
      int r = i * 32 + w * 8;      // wave-uniform chunk base row
      gl_lds16(Ag + (long)(r + srow) * K + k0 + sg * 8, &As[r * 64]);
    }
#pragma unroll
    for (int i = 0; i < BN / 32; ++i) {
      int r = i * 32 + w * 8;
      gl_lds16(Bg + (long)(r + srow) * K + k0 + sg * 8, &Bs[r * 64]);
    }
    __syncthreads();               // drains vmcnt(0): tiles resident
    __builtin_amdgcn_s_setprio(1);
#pragma unroll
    for (int ks = 0; ks < 2; ++ks) {
      bf16x8 af[4], bfr[FN];
#pragma unroll
      for (int m = 0; m < 4; ++m)
        af[m]  = *(const bf16x8*)&As[(wr + m * 16 + fr) * 64 + (((ks * 4 + fq) ^ (fr & 7)) << 3)];
#pragma unroll
      for (int n = 0; n < FN; ++n)
        bfr[n] = *(const bf16x8*)&Bs[(wc + n * 16 + fr) * 64 + (((ks * 4 + fq) ^ (fr & 7)) << 3)];
#pragma unroll
      for (int m = 0; m < 4; ++m)
#pragma unroll
        for (int n = 0; n < FN; ++n)
          acc[m][n] = __builtin_amdgcn_mfma_f32_16x16x32_bf16(af[m], bfr[n], acc[m][n], 0, 0, 0);
    }
    __builtin_amdgcn_s_setprio(0);
  }
  // epilogue: C/D layout col=lane&15, row=(lane>>4)*4+reg
#pragma unroll
  for (int m = 0; m < 4; ++m) {
    int row0 = bm + wr + m * 16 + fq * 4;
#pragma unroll
    for (int n = 0; n < FN; ++n) {
      int col = bn + wc + n * 16 + fr;
      float bv = BIAS ? bias[col] : 0.0f;
#pragma unroll
      for (int j = 0; j < 4; ++j)
        C[(long)(row0 + j) * N + col] = acc[m][n][j] + bv;
    }
  }
}

// ---------------- fused RMSNorm + RoPE for q,k; writes bf16 [h][t][d] ----------------
__global__ __launch_bounds__(256)
void normrope_qk(const float* __restrict__ qkv, const float* __restrict__ cosd,
                 const float* __restrict__ sind, unsigned short* __restrict__ qb,
                 unsigned short* __restrict__ kb) {
  const int wgl  = (blockIdx.x * 256 + threadIdx.x) >> 6;  // global wave id 0..4095
  const int lane = threadIdx.x & 63;
  for (int rr = wgl; rr < T_SEQ * 32; rr += 4096) {
    const int t = rr >> 5;
    const int y = rr & 31;               // 0..15 q heads, 16..31 k heads
    const float2 v = *(const float2*)(qkv + (long)t * QKVN + y * 128 + lane * 2);
    float ss = v.x * v.x + v.y * v.y;
#pragma unroll
    for (int m = 1; m < 64; m <<= 1) ss += __shfl_xor(ss, m, 64);
    const float r = rsqrtf(ss * (1.0f / 128.0f) + 1.1920928955078125e-07f);
    const float a = v.x * r, b = v.y * r;
    const float pa = __shfl_xor(a, 32, 64), pb = __shfl_xor(b, 32, 64);
    const float2 c2 = *(const float2*)(cosd + t * 64 + (lane & 31) * 2);
    const float2 s2 = *(const float2*)(sind + t * 64 + (lane & 31) * 2);
    float o0, o1;
    if (lane < 32) { o0 =  a * c2.x + pa * s2.x;  o1 =  b * c2.y + pb * s2.y; }
    else           { o0 = -pa * s2.x + a * c2.x;  o1 = -pb * s2.y + b * c2.y; }
    unsigned short* dst = (y >> 4) ? kb : qb;
    const unsigned int packed = (unsigned int)f2bf(o0) | ((unsigned int)f2bf(o1) << 16);
    *(unsigned int*)(dst + ((long)(y & 15) * T_SEQ + t) * 128 + lane * 2) = packed;
  }
}

// ---------------- V: cast + transpose to [h][d][t] bf16 ----------------
__global__ __launch_bounds__(256)
void v_transpose(const float* __restrict__ qkv, unsigned short* __restrict__ vt) {
  const int tb = blockIdx.x;   // 64-row t tile
  const int h  = blockIdx.y;
  __shared__ unsigned short vl[128][72];   // pad: row stride 144B (16B aligned)
  const int tid = threadIdx.x;
#pragma unroll
  for (int p = 0; p < 32; ++p) {
    int rr = p * 2 + (tid >> 7);
    int d  = tid & 127;
    float x = qkv[(long)(tb * 64 + rr) * QKVN + 2 * HS + h * 128 + d];
    vl[d][rr] = f2bf(x);
  }
  __syncthreads();
#pragma unroll
  for (int p = 0; p < 8; ++p) {
    int idx = (p * 256 + tid) * 4;   // elem in [128][64]
    int d = idx >> 6;
    int i = idx & 63;
    us4 val = *(const us4*)&vl[d][i];
    *(us4*)&vt[((long)h * DH + d) * T_SEQ + tb * 64 + i] = val;
  }
}

// ---------------- causal flash attention, QBLK=128, cross-block split-K ----------------
// 512 blocks x 512 thr (8 waves, each owning 16 of 128 q-rows). Each (Q,h) handled
// by TWO blocks: p0 kt in [0,Q], p1 kt in [Q+1,2Q+1] (both Q+1 tiles; no empty parts).
// Map: bi<256 -> (Q=15-(bi>>4), p0) heavy-first; bi>=256 -> (Q=(bi-256)>>4, p1).
// Co-resident pair sums = 17 tiles. One K/V staging + 2 barriers now serve 8 waves
// (2x less staging/barrier per wave-work vs QBLK=64). LDS 50KB -> 3 blocks/CU
// capacity (VGPR ~80 -> 6 waves/SIMD fits 24 waves). T14 reg-staging, single buffer.
__global__ __launch_bounds__(512, 4)
void attn_kernel(const unsigned short* __restrict__ qg, const unsigned short* __restrict__ kg,
                 const unsigned short* __restrict__ vtg, float* __restrict__ accG,
                 float* __restrict__ mlG) {
  const int bi = blockIdx.x;
  const int j  = bi & 255;
  const int h  = j & 15;
  const int Q0 = j >> 4;                  // 0..15
  const int p  = bi >> 8;                 // 0 or 1
  const int Q  = p ? Q0 : (15 - Q0);
  const int slot = (Q * 16 + h) * 2 + p;
  const int kt0 = p ? (Q + 1) : 0;
  const int kte = p ? (2 * Q + 1) : Q;

  const int tid = threadIdx.x, lane = tid & 63, w = tid >> 6;   // w 0..7
  const int fr = lane & 15, fq = lane >> 4;

  float* accO = accG + (long)slot * 16384;   // [128][128] f32
  float* mlO  = mlG + slot * 256;            // m[128], l[128]

  __shared__ unsigned short Ks[64 * 128];    // 16KB single buffer
  __shared__ unsigned short Vts[128 * 64];   // 16KB single buffer
  __shared__ unsigned short Ps[8][16 * 72];  // 18KB -> total 50KB

  const unsigned short* qh = qg  + (long)h * T_SEQ * 128;
  const unsigned short* kh = kg  + (long)h * T_SEQ * 128;
  const unsigned short* vh = vtg + (long)h * 128 * T_SEQ;

  // reg-staging: 512 threads x 2 granules (16B) each for K and V.
  // K granule g=tid+512i: row=g>>4, pos=g&15 (linear global read).
  // V granule g: d=g>>3, vpos=g&7. LDS write applies XOR swizzle.
  us8 kreg[2], vreg[2];

  // prologue: tile kt0 -> regs -> LDS
  {
    const unsigned short* ksrc = kh + (long)kt0 * 8192;
#pragma unroll
    for (int i = 0; i < 2; ++i) {
      int g = tid + 512 * i;
      int row = g >> 4, pos = g & 15;
      kreg[i] = *(const us8*)(ksrc + row * 128 + pos * 8);
      int d = g >> 3, vpos = g & 7;
      vreg[i] = *(const us8*)(vh + (long)d * T_SEQ + kt0 * 64 + vpos * 8);
    }
#pragma unroll
    for (int i = 0; i < 2; ++i) {
      int g = tid + 512 * i;
      int row = g >> 4, pos = g & 15;
      *(us8*)&Ks[row * 128 + ((pos ^ (row & 7)) << 3)] = kreg[i];
      int d = g >> 3, vpos = g & 7;
      *(us8*)&Vts[d * 64 + ((vpos ^ (d & 7)) << 3)] = vreg[i];
    }
  }

  // Q fragments straight from global (wave w owns rows Q*128 + w*16 + [0,16))
  bf16x8 aq[4];
  {
    const unsigned short* qrow = qh + (long)(Q * 128 + w * 16 + fr) * 128;
#pragma unroll
    for (int ks = 0; ks < 4; ++ks)
      aq[ks] = *(const bf16x8*)(qrow + ks * 32 + fq * 8);
  }

  // ones B-fragment for the row-sum MFMA
  bf16x8 vone;
#pragma unroll
  for (int e = 0; e < 8; ++e) vone[e] = (short)0x3F80;

  f32x4 acc[8];
#pragma unroll
  for (int n = 0; n < 8; ++n) { acc[n][0]=0.f; acc[n][1]=0.f; acc[n][2]=0.f; acc[n][3]=0.f; }
  f32x4 accS;  accS[0]=0.f; accS[1]=0.f; accS[2]=0.f; accS[3]=0.f;   // row-sums
  float mrow[4];
#pragma unroll
  for (int j2 = 0; j2 < 4; ++j2) mrow[j2] = -1e30f;

  const float scale2 = 0.08838834764831845f * 1.4426950408889634f;   // 1/sqrt(128) * log2e

  __syncthreads();   // tile kt0 resident in LDS

  for (int kt = kt0; kt <= kte; ++kt) {
    // issue next tile's global->reg loads; latency hides under this tile's compute
    if (kt < kte) {
      const unsigned short* ksrc = kh + (long)(kt + 1) * 8192;
#pragma unroll
      for (int i = 0; i < 2; ++i) {
        int g = tid + 512 * i;
        int row = g >> 4, pos = g & 15;
        kreg[i] = *(const us8*)(ksrc + row * 128 + pos * 8);
        int d = g >> 3, vpos = g & 7;
        vreg[i] = *(const us8*)(vh + (long)d * T_SEQ + (kt + 1) * 64 + vpos * 8);
      }
    }

    // S = Q K^T (16 x 64 per wave), in log2 units
    f32x4 sv[4];
#pragma unroll
    for (int n = 0; n < 4; ++n) { sv[n][0]=0.f; sv[n][1]=0.f; sv[n][2]=0.f; sv[n][3]=0.f; }
    __builtin_amdgcn_s_setprio(1);
#pragma unroll
    for (int ks = 0; ks < 4; ++ks)
#pragma unroll
      for (int n = 0; n < 4; ++n) {
        int R = n * 16 + fr;
        bf16x8 bk = *(const bf16x8*)&Ks[R * 128 + (((ks * 4 + fq) ^ (fr & 7)) << 3)];
        sv[n] = __builtin_amdgcn_mfma_f32_16x16x32_bf16(aq[ks], bk, sv[n], 0, 0, 0);
      }
    __builtin_amdgcn_s_setprio(0);

    // scale(log2); causal mask only possible when kt >= 2Q (col > row never holds below)
#pragma unroll
    for (int n = 0; n < 4; ++n)
#pragma unroll
      for (int j3 = 0; j3 < 4; ++j3) sv[n][j3] *= scale2;
    if (kt >= (Q << 1)) {
#pragma unroll
      for (int n = 0; n < 4; ++n)
#pragma unroll
        for (int j3 = 0; j3 < 4; ++j3) {
          int col = kt * 64 + n * 16 + fr;
          int rowg = Q * 128 + w * 16 + fq * 4 + j3;
          if (col > rowg) sv[n][j3] = -1e30f;
        }
    }

    // row max over 64 cols
    float pm[4];
#pragma unroll
    for (int j3 = 0; j3 < 4; ++j3)
      pm[j3] = fmaxf(fmaxf(sv[0][j3], sv[1][j3]), fmaxf(sv[2][j3], sv[3][j3]));
#pragma unroll
    for (int m = 1; m < 16; m <<= 1)
#pragma unroll
      for (int j3 = 0; j3 < 4; ++j3) pm[j3] = fmaxf(pm[j3], __shfl_xor(pm[j3], m, 64));

    // defer-rescale: only when some row's max grew
    bool grow = (pm[0] > mrow[0]) | (pm[1] > mrow[1]) | (pm[2] > mrow[2]) | (pm[3] > mrow[3]);
    if (__any(grow)) {
      float alpha[4];
#pragma unroll
      for (int j3 = 0; j3 < 4; ++j3) {
        float mn = fmaxf(mrow[j3], pm[j3]);
        alpha[j3] = exp2f(mrow[j3] - mn);
        mrow[j3] = mn;
      }
#pragma unroll
      for (int n = 0; n < 8; ++n)
#pragma unroll
        for (int j3 = 0; j3 < 4; ++j3) acc[n][j3] *= alpha[j3];
#pragma unroll
      for (int j3 = 0; j3 < 4; ++j3) accS[j3] *= alpha[j3];
    }

    // P = exp2(S - m), bf16 -> per-wave LDS
    unsigned short* pl = &Ps[w][0];
#pragma unroll
    for (int n = 0; n < 4; ++n)
#pragma unroll
      for (int j3 = 0; j3 < 4; ++j3)
        pl[(fq * 4 + j3) * 72 + n * 16 + fr] = f2bf(exp2f(sv[n][j3] - mrow[j3]));
    asm volatile("s_waitcnt lgkmcnt(0)" ::: "memory");
    __builtin_amdgcn_s_setprio(1);
#pragma unroll
    for (int ks = 0; ks < 2; ++ks) {
      bf16x8 pa = *(const bf16x8*)&pl[fr * 72 + ks * 32 + fq * 8];
      accS = __builtin_amdgcn_mfma_f32_16x16x32_bf16(pa, vone, accS, 0, 0, 0);
#pragma unroll
      for (int n = 0; n < 8; ++n) {
        int R = n * 16 + fr;
        bf16x8 bv = *(const bf16x8*)&Vts[R * 64 + (((ks * 4 + fq) ^ (fr & 7)) << 3)];
        acc[n] = __builtin_amdgcn_mfma_f32_16x16x32_bf16(pa, bv, acc[n], 0, 0, 0);
      }
    }
    __builtin_amdgcn_s_setprio(0);

    __syncthreads();   // all waves done READING this tile's LDS
    if (kt < kte) {    // park staged regs into LDS (vmcnt auto-waited on first use)
#pragma unroll
      for (int i = 0; i < 2; ++i) {
        int g = tid + 512 * i;
        int row = g >> 4, pos = g & 15;
        *(us8*)&Ks[row * 128 + ((pos ^ (row & 7)) << 3)] = kreg[i];
        int d = g >> 3, vpos = g & 7;
        *(us8*)&Vts[d * 64 + ((vpos ^ (d & 7)) << 3)] = vreg[i];
      }
    }
    __syncthreads();   // writes visible to all waves
  }

  // write partials (m in log2 units, l = row-sum from accS)
#pragma unroll
  for (int j3 = 0; j3 < 4; ++j3) {
    int row = w * 16 + fq * 4 + j3;
#pragma unroll
    for (int n = 0; n < 8; ++n)
      accO[row * 128 + n * 16 + fr] = acc[n][j3];
    if (fr == 0) { mlO[row] = mrow[j3]; mlO[128 + row] = accS[j3]; }
  }
}

// ---------------- combine split-K partials -> yb bf16 (exp2-domain m) ----------------
// 256 blocks (Q*16+h), 256 thr; merges two [128][128] partials.
__global__ __launch_bounds__(256)
void attn_combine(const float* __restrict__ accG, const float* __restrict__ mlG,
                  unsigned short* __restrict__ yb) {
  const int j = blockIdx.x;
  const int Q = j >> 4, h = j & 15;
  const float* a0 = accG + (long)(j * 2 + 0) * 16384;
  const float* a1 = accG + (long)(j * 2 + 1) * 16384;
  const float* ml0 = mlG + (j * 2 + 0) * 256;
  const float* ml1 = mlG + (j * 2 + 1) * 256;
  const int tid = threadIdx.x;
#pragma unroll
  for (int e = 0; e < 16; ++e) {
    int idx = e * 256 + tid;            // 0..4095, covers [128][32] f32x4 slots
    int row = idx >> 5;
    int c4  = (idx & 31) * 4;
    float m0 = ml0[row], l0 = ml0[128 + row];
    float m1 = ml1[row], l1 = ml1[128 + row];
    float m  = fmaxf(m0, m1);
    float w0 = exp2f(m0 - m), w1 = exp2f(m1 - m);
    float inv = 1.0f / (l0 * w0 + l1 * w1);
    f32x4 A = *(const f32x4*)(a0 + row * 128 + c4);
    f32x4 B = *(const f32x4*)(a1 + row * 128 + c4);
    us4 o;
#pragma unroll
    for (int q = 0; q < 4; ++q)
      o[q] = f2bf((A[q] * w0 + B[q] * w1) * inv);
    *(us4*)(yb + (long)(Q * 128 + row) * HS + h * 128 + c4) = o;
  }
}

// ---------------- launch ----------------
extern "C" void kernel_launch(void* const* d_in, const int* in_sizes, int n_in,
                              void* d_out, int out_size, void* d_ws, size_t ws_size,
                              hipStream_t stream) {
  const float* x    = (const float*)d_in[0];
  const float* Wqkv = (const float*)d_in[1];
  const float* Wo_w = (const float*)d_in[2];
  const float* Wo_b = (const float*)d_in[3];
  float* out = (float*)d_out;
  char* ws = (char*)d_ws;

  unsigned short* xbf  = (unsigned short*)(ws + 0L);          //  8.0 MB
  unsigned short* wqbf = (unsigned short*)(ws + 8388608L);    // 24.0 MB
  unsigned short* wobf = (unsigned short*)(ws + 33554432L);   //  8.0 MB
  float*          qkv  = (float*)         (ws + 41943040L);   // 48.0 MB
  unsigned short* qb   = (unsigned short*)(ws + 92274688L);   //  8.0 MB
  unsigned short* kb   = (unsigned short*)(ws + 100663296L);  //  8.0 MB
  unsigned short* vt   = (unsigned short*)(ws + 109051904L);  //  8.0 MB
  unsigned short* yb   = (unsigned short*)(ws + 117440512L);  //  8.0 MB
  float*          cosd = (float*)         (ws + 125829120L);  //  0.5 MB
  float*          sind = (float*)         (ws + 126353408L);  //  0.5 MB
  // overlays (dead by the time attn runs): acc partials over xbf+wqbf, m/l over qkv
  float*          accG = (float*)         (ws + 0L);          // 32.0 MB (512 x 128 x 128 f32)
  float*          mlG  = (float*)         (ws + 41943040L);   //  0.5 MB (512 x 256 f32)

  cast_bf16_kernel<<<dim3(4194304 / 8 / 256), 256, 0, stream>>>(x, xbf, 4194304);
  cast_bf16_kernel<<<dim3(12582912 / 8 / 256), 256, 0, stream>>>(Wqkv, wqbf, 12582912);
  cast_bf16_kernel<<<dim3(4194304 / 8 / 256), 256, 0, stream>>>(Wo_w, wobf, 4194304);
  rope_table_kernel<<<dim3(512), 256, 0, stream>>>(cosd, sind);

  gemm_bt<0, 128><<<dim3(QKVN / 128, T_SEQ / 128), 256, 0, stream>>>(xbf, wqbf, qkv, nullptr,
                                                                     T_SEQ, QKVN, HS);
  normrope_qk<<<dim3(1024), 256, 0, stream>>>(qkv, cosd, sind, qb, kb);
  v_transpose<<<dim3(T_SEQ / 64, NH), 256, 0, stream>>>(qkv, vt);
  attn_kernel<<<dim3(512), 512, 0, stream>>>(qb, kb, vt, accG, mlG);
  attn_combine<<<dim3(256), 256, 0, stream>>>(accG, mlG, yb);
  gemm_bt<1, 64><<<dim3(HS / 64, T_SEQ / 128), 256, 0, stream>>>(yb, wobf, out, Wo_b,
                                                                 T_SEQ, HS, HS);
}

// Round 13
// 278.705 us; speedup vs baseline: 1.0806x; 1.0806x over previous
//
#include <hip/hip_runtime.h>
#include <hip/hip_bf16.h>
#include <stdint.h>

#define T_SEQ 2048
#define HS    2048
#define NH    16
#define DH    128
#define QKVN  (3*HS)

typedef __attribute__((ext_vector_type(8))) short          bf16x8;
typedef __attribute__((ext_vector_type(4))) float          f32x4;
typedef __attribute__((ext_vector_type(4))) unsigned short us4;
typedef __attribute__((ext_vector_type(8))) unsigned short us8;

// round-to-nearest-even f32 -> bf16 bits
__device__ __forceinline__ unsigned short f2bf(float x) {
  unsigned int u = __float_as_uint(x);
  return (unsigned short)((u + 0x7fffu + ((u >> 16) & 1u)) >> 16);
}
__device__ __forceinline__ float bf2f(unsigned short b) {
  return __uint_as_float(((unsigned int)b) << 16);
}

// async global->LDS, 16B per lane; lds base must be wave-uniform (lane i lands at base + i*16B)
__device__ __forceinline__ void gl_lds16(const void* g, void* l) {
  __builtin_amdgcn_global_load_lds((__attribute__((address_space(1))) void*)g,
                                   (__attribute__((address_space(3))) void*)l, 16, 0, 0);
}

// ---------------- elementwise cast f32 -> bf16 (vectorized 8/thread) ----------------
__global__ __launch_bounds__(256) void cast_bf16_kernel(const float* __restrict__ in,
                                                        unsigned short* __restrict__ out, int n) {
  int i = (blockIdx.x * 256 + threadIdx.x) * 8;
  if (i >= n) return;
  f32x4 a = *(const f32x4*)(in + i);
  f32x4 b = *(const f32x4*)(in + i + 4);
  us8 r;
#pragma unroll
  for (int j = 0; j < 4; ++j) { r[j] = f2bf(a[j]); r[j + 4] = f2bf(b[j]); }
  *(us8*)(out + i) = r;
}

// ---------------- RoPE cos/sin table [T][64] ----------------
__global__ __launch_bounds__(256) void rope_table_kernel(float* __restrict__ cosd,
                                                         float* __restrict__ sind) {
  int i = blockIdx.x * 256 + threadIdx.x;   // over T*64
  if (i >= T_SEQ * 64) return;
  int t = i >> 6, f = i & 63;
  float inv = expf(-9.210340371976184f * (float)f * (1.0f / 64.0f));
  float ang = (float)t * inv;
  float s, c;
  sincosf(ang, &s, &c);
  cosd[i] = c; sind[i] = s;
}

// ---------------- GEMM C[M][N] = A[M][K](bf16) * Bt[N][K](bf16)^T (+bias) ----------------
// OBF=1: write bf16 output (half the C traffic); OBF=0: f32 (+bias).
template <int BIAS, int BN, int OBF>
__global__ __launch_bounds__(256, 4)
void gemm_bt(const unsigned short* __restrict__ A, const unsigned short* __restrict__ Bt,
             void* __restrict__ Cv, const float* __restrict__ bias, int M, int N, int K) {
  constexpr int FN = BN / 32;          // n-fragments per wave (128->4, 64->2)
  __shared__ unsigned short As[128 * 64];
  __shared__ unsigned short Bs[BN * 64];
  const int tid  = threadIdx.x;
  const int lane = tid & 63;
  const int w    = tid >> 6;
  const int fr   = lane & 15;   // fragment row/col
  const int fq   = lane >> 4;   // k-group
  const int bm   = blockIdx.y * 128;
  const int bn   = blockIdx.x * BN;
  const int wr   = (w >> 1) * 64;
  const int wc   = (w & 1) * (BN / 2);

  f32x4 acc[4][FN];
#pragma unroll
  for (int m = 0; m < 4; ++m)
#pragma unroll
    for (int n = 0; n < FN; ++n) { acc[m][n][0]=0.f; acc[m][n][1]=0.f; acc[m][n][2]=0.f; acc[m][n][3]=0.f; }

  const int srow = lane >> 3;
  const int sg   = (lane & 7) ^ srow;
  const unsigned short* Ag = A + (long)bm * K;
  const unsigned short* Bg = Bt + (long)bn * K;

  const int nk = K >> 6;
  for (int kt = 0; kt < nk; ++kt) {
    const int k0 = kt << 6;
    __syncthreads();               // previous compute done, LDS free
#pragma unroll
    for (int i = 0; i < 4; ++i) {
      int r = i * 32 + w * 8;      // wave-uniform chunk base row
      gl_lds16(Ag + (long)(r + srow) * K + k0 + sg * 8, &As[r * 64]);
    }
#pragma unroll
    for (int i = 0; i < BN / 32; ++i) {
      int r = i * 32 + w * 8;
      gl_lds16(Bg + (long)(r + srow) * K + k0 + sg * 8, &Bs[r * 64]);
    }
    __syncthreads();               // drains vmcnt(0): tiles resident
    __builtin_amdgcn_s_setprio(1);
#pragma unroll
    for (int ks = 0; ks < 2; ++ks) {
      bf16x8 af[4], bfr[FN];
#pragma unroll
      for (int m = 0; m < 4; ++m)
        af[m]  = *(const bf16x8*)&As[(wr + m * 16 + fr) * 64 + (((ks * 4 + fq) ^ (fr & 7)) << 3)];
#pragma unroll
      for (int n = 0; n < FN; ++n)
        bfr[n] = *(const bf16x8*)&Bs[(wc + n * 16 + fr) * 64 + (((ks * 4 + fq) ^ (fr & 7)) << 3)];
#pragma unroll
      for (int m = 0; m < 4; ++m)
#pragma unroll
        for (int n = 0; n < FN; ++n)
          acc[m][n] = __builtin_amdgcn_mfma_f32_16x16x32_bf16(af[m], bfr[n], acc[m][n], 0, 0, 0);
    }
    __builtin_amdgcn_s_setprio(0);
  }
  // epilogue: C/D layout col=lane&15, row=(lane>>4)*4+reg
#pragma unroll
  for (int m = 0; m < 4; ++m) {
    int row0 = bm + wr + m * 16 + fq * 4;
#pragma unroll
    for (int n = 0; n < FN; ++n) {
      int col = bn + wc + n * 16 + fr;
      float bv = BIAS ? bias[col] : 0.0f;
#pragma unroll
      for (int j = 0; j < 4; ++j) {
        if constexpr (OBF) {
          ((unsigned short*)Cv)[(long)(row0 + j) * N + col] = f2bf(acc[m][n][j] + bv);
        } else {
          ((float*)Cv)[(long)(row0 + j) * N + col] = acc[m][n][j] + bv;
        }
      }
    }
  }
}

// ---------------- fused RMSNorm + RoPE for q,k (bf16 qkv in); writes bf16 [h][t][d] ----------------
__global__ __launch_bounds__(256)
void normrope_qk(const unsigned short* __restrict__ qkv, const float* __restrict__ cosd,
                 const float* __restrict__ sind, unsigned short* __restrict__ qb,
                 unsigned short* __restrict__ kb) {
  const int wgl  = (blockIdx.x * 256 + threadIdx.x) >> 6;  // global wave id 0..4095
  const int lane = threadIdx.x & 63;
  for (int rr = wgl; rr < T_SEQ * 32; rr += 4096) {
    const int t = rr >> 5;
    const int y = rr & 31;               // 0..15 q heads, 16..31 k heads
    const unsigned int pk = *(const unsigned int*)(qkv + (long)t * QKVN + y * 128 + lane * 2);
    const float vx = bf2f((unsigned short)(pk & 0xFFFF));
    const float vy = bf2f((unsigned short)(pk >> 16));
    float ss = vx * vx + vy * vy;
#pragma unroll
    for (int m = 1; m < 64; m <<= 1) ss += __shfl_xor(ss, m, 64);
    const float r = rsqrtf(ss * (1.0f / 128.0f) + 1.1920928955078125e-07f);
    const float a = vx * r, b = vy * r;
    const float pa = __shfl_xor(a, 32, 64), pb = __shfl_xor(b, 32, 64);
    const float2 c2 = *(const float2*)(cosd + t * 64 + (lane & 31) * 2);
    const float2 s2 = *(const float2*)(sind + t * 64 + (lane & 31) * 2);
    float o0, o1;
    if (lane < 32) { o0 =  a * c2.x + pa * s2.x;  o1 =  b * c2.y + pb * s2.y; }
    else           { o0 = -pa * s2.x + a * c2.x;  o1 = -pb * s2.y + b * c2.y; }
    unsigned short* dst = (y >> 4) ? kb : qb;
    const unsigned int packed = (unsigned int)f2bf(o0) | ((unsigned int)f2bf(o1) << 16);
    *(unsigned int*)(dst + ((long)(y & 15) * T_SEQ + t) * 128 + lane * 2) = packed;
  }
}

// ---------------- V: transpose bf16 qkv -> [h][d][t] bf16 ----------------
__global__ __launch_bounds__(256)
void v_transpose(const unsigned short* __restrict__ qkv, unsigned short* __restrict__ vt) {
  const int tb = blockIdx.x;   // 64-row t tile
  const int h  = blockIdx.y;
  __shared__ unsigned short vl[128][72];   // pad: row stride 144B (16B aligned)
  const int tid = threadIdx.x;
#pragma unroll
  for (int p = 0; p < 32; ++p) {
    int rr = p * 2 + (tid >> 7);
    int d  = tid & 127;
    vl[d][rr] = qkv[(long)(tb * 64 + rr) * QKVN + 2 * HS + h * 128 + d];
  }
  __syncthreads();
#pragma unroll
  for (int p = 0; p < 8; ++p) {
    int idx = (p * 256 + tid) * 4;   // elem in [128][64]
    int d = idx >> 6;
    int i = idx & 63;
    us4 val = *(const us4*)&vl[d][i];
    *(us4*)&vt[((long)h * DH + d) * T_SEQ + tb * 64 + i] = val;
  }
}

// ---------------- causal flash attention, cross-block split-K ----------------
// 1024 blocks x 256 thr (4 waves); (qb,h) handled by two blocks (p0/p1 K-ranges).
// T14 reg-staging: next K/V tile is loaded global->REGISTERS during compute,
// then ds_written into SINGLE-buffered LDS (write-side XOR swizzle) after a
// read-done barrier. LDS 41KB -> 3 blocks/CU. Quarter map keeps per-CU cost sum.
__global__ __launch_bounds__(256, 3)
void attn_kernel(const unsigned short* __restrict__ qg, const unsigned short* __restrict__ kg,
                 const unsigned short* __restrict__ vtg, float* __restrict__ accG,
                 float* __restrict__ mlG) {
  const int bi = blockIdx.x;
  const int q0 = (bi & 255) >> 4;
  const int h  = bi & 15;
  const int quarter = bi >> 8;
  const int qb = (quarter < 2) ? (31 - q0) : q0;
  const int p  = quarter & 1;
  const int slot = (qb * 16 + h) * 2 + p;

  const int kt0 = p ? ((qb >> 1) + 1) : 0;
  const int kte = p ? qb : (qb >> 1);

  const int tid = threadIdx.x, lane = tid & 63, w = tid >> 6;
  const int fr = lane & 15, fq = lane >> 4;

  float* accO = accG + (long)slot * 8192;
  float* mlO  = mlG + slot * 128;

  if (kt0 > kte) {   // empty K-range (qb==0, p1): neutral stats only (uniform branch)
#pragma unroll
    for (int j3 = 0; j3 < 4; ++j3) {
      int row = w * 16 + fq * 4 + j3;
      if (fr == 0) { mlO[row] = -1e30f; mlO[64 + row] = 0.f; }
    }
    return;
  }

  __shared__ unsigned short Ks[64 * 128];    // 16KB single buffer
  __shared__ unsigned short Vts[128 * 64];   // 16KB single buffer
  __shared__ unsigned short Ps[4][16 * 72];  // 9.2KB  -> total 41.2KB, 3 blocks/CU

  const unsigned short* qh = qg  + (long)h * T_SEQ * 128;
  const unsigned short* kh = kg  + (long)h * T_SEQ * 128;
  const unsigned short* vh = vtg + (long)h * 128 * T_SEQ;

  // reg-staging geometry: thread owns 4 K-granules + 4 V-granules (16B each).
  us8 kreg[4], vreg[4];

  // prologue: tile kt0 -> regs -> LDS
  {
    const unsigned short* ksrc = kh + (long)kt0 * 8192;
#pragma unroll
    for (int i = 0; i < 4; ++i) {
      int gidx = tid + 256 * i;
      int row = gidx >> 4, pos = gidx & 15;
      kreg[i] = *(const us8*)(ksrc + row * 128 + pos * 8);
      int d = gidx >> 3, vpos = gidx & 7;
      vreg[i] = *(const us8*)(vh + (long)d * T_SEQ + kt0 * 64 + vpos * 8);
    }
#pragma unroll
    for (int i = 0; i < 4; ++i) {
      int gidx = tid + 256 * i;
      int row = gidx >> 4, pos = gidx & 15;
      *(us8*)&Ks[row * 128 + ((pos ^ (row & 7)) << 3)] = kreg[i];
      int d = gidx >> 3, vpos = gidx & 7;
      *(us8*)&Vts[d * 64 + ((vpos ^ (d & 7)) << 3)] = vreg[i];
    }
  }

  // Q fragments straight from global
  bf16x8 aq[4];
  {
    const unsigned short* qrow = qh + (long)(qb * 64 + w * 16 + fr) * 128;
#pragma unroll
    for (int ks = 0; ks < 4; ++ks)
      aq[ks] = *(const bf16x8*)(qrow + ks * 32 + fq * 8);
  }

  // ones B-fragment for the row-sum MFMA
  bf16x8 vone;
#pragma unroll
  for (int e = 0; e < 8; ++e) vone[e] = (short)0x3F80;

  f32x4 acc[8];
#pragma unroll
  for (int n = 0; n < 8; ++n) { acc[n][0]=0.f; acc[n][1]=0.f; acc[n][2]=0.f; acc[n][3]=0.f; }
  f32x4 accS;  accS[0]=0.f; accS[1]=0.f; accS[2]=0.f; accS[3]=0.f;   // row-sums
  float mrow[4];
#pragma unroll
  for (int j2 = 0; j2 < 4; ++j2) mrow[j2] = -1e30f;

  const float scale2 = 0.08838834764831845f * 1.4426950408889634f;   // 1/sqrt(128) * log2e

  __syncthreads();   // tile kt0 resident in LDS

  for (int kt = kt0; kt <= kte; ++kt) {
    // issue next tile's global->reg loads; latency hides under this tile's compute
    if (kt < kte) {
      const unsigned short* ksrc = kh + (long)(kt + 1) * 8192;
#pragma unroll
      for (int i = 0; i < 4; ++i) {
        int gidx = tid + 256 * i;
        int row = gidx >> 4, pos = gidx & 15;
        kreg[i] = *(const us8*)(ksrc + row * 128 + pos * 8);
        int d = gidx >> 3, vpos = gidx & 7;
        vreg[i] = *(const us8*)(vh + (long)d * T_SEQ + (kt + 1) * 64 + vpos * 8);
      }
    }

    // S = Q K^T (16 x 64 per wave), in log2 units
    f32x4 sv[4];
#pragma unroll
    for (int n = 0; n < 4; ++n) { sv[n][0]=0.f; sv[n][1]=0.f; sv[n][2]=0.f; sv[n][3]=0.f; }
    __builtin_amdgcn_s_setprio(1);
#pragma unroll
    for (int ks = 0; ks < 4; ++ks)
#pragma unroll
      for (int n = 0; n < 4; ++n) {
        int R = n * 16 + fr;
        bf16x8 bk = *(const bf16x8*)&Ks[R * 128 + (((ks * 4 + fq) ^ (fr & 7)) << 3)];
        sv[n] = __builtin_amdgcn_mfma_f32_16x16x32_bf16(aq[ks], bk, sv[n], 0, 0, 0);
      }
    __builtin_amdgcn_s_setprio(0);

    // scale(log2) + causal mask (diagonal tile only)
#pragma unroll
    for (int n = 0; n < 4; ++n)
#pragma unroll
      for (int j3 = 0; j3 < 4; ++j3) {
        float s = sv[n][j3] * scale2;
        if (kt == qb && (n * 16 + fr) > (w * 16 + fq * 4 + j3)) s = -1e30f;
        sv[n][j3] = s;
      }

    // row max over 64 cols
    float pm[4];
#pragma unroll
    for (int j3 = 0; j3 < 4; ++j3)
      pm[j3] = fmaxf(fmaxf(sv[0][j3], sv[1][j3]), fmaxf(sv[2][j3], sv[3][j3]));
#pragma unroll
    for (int m = 1; m < 16; m <<= 1)
#pragma unroll
      for (int j3 = 0; j3 < 4; ++j3) pm[j3] = fmaxf(pm[j3], __shfl_xor(pm[j3], m, 64));

    // defer-rescale: only when some row's max grew
    bool grow = (pm[0] > mrow[0]) | (pm[1] > mrow[1]) | (pm[2] > mrow[2]) | (pm[3] > mrow[3]);
    if (__any(grow)) {
      float alpha[4];
#pragma unroll
      for (int j3 = 0; j3 < 4; ++j3) {
        float mn = fmaxf(mrow[j3], pm[j3]);
        alpha[j3] = exp2f(mrow[j3] - mn);
        mrow[j3] = mn;
      }
#pragma unroll
      for (int n = 0; n < 8; ++n)
#pragma unroll
        for (int j3 = 0; j3 < 4; ++j3) acc[n][j3] *= alpha[j3];
#pragma unroll
      for (int j3 = 0; j3 < 4; ++j3) accS[j3] *= alpha[j3];
    }

    // P = exp2(S - m), bf16 -> per-wave LDS
    unsigned short* pl = &Ps[w][0];
#pragma unroll
    for (int n = 0; n < 4; ++n)
#pragma unroll
      for (int j3 = 0; j3 < 4; ++j3)
        pl[(fq * 4 + j3) * 72 + n * 16 + fr] = f2bf(exp2f(sv[n][j3] - mrow[j3]));
    asm volatile("s_waitcnt lgkmcnt(0)" ::: "memory");
    __builtin_amdgcn_s_setprio(1);
#pragma unroll
    for (int ks = 0; ks < 2; ++ks) {
      bf16x8 pa = *(const bf16x8*)&pl[fr * 72 + ks * 32 + fq * 8];
      accS = __builtin_amdgcn_mfma_f32_16x16x32_bf16(pa, vone, accS, 0, 0, 0);
#pragma unroll
      for (int n = 0; n < 8; ++n) {
        int R = n * 16 + fr;
        bf16x8 bv = *(const bf16x8*)&Vts[R * 64 + (((ks * 4 + fq) ^ (fr & 7)) << 3)];
        acc[n] = __builtin_amdgcn_mfma_f32_16x16x32_bf16(pa, bv, acc[n], 0, 0, 0);
      }
    }
    __builtin_amdgcn_s_setprio(0);

    __syncthreads();   // all waves done READING this tile's LDS
    if (kt < kte) {    // park staged regs into LDS (vmcnt auto-waited on first use)
#pragma unroll
      for (int i = 0; i < 4; ++i) {
        int gidx = tid + 256 * i;
        int row = gidx >> 4, pos = gidx & 15;
        *(us8*)&Ks[row * 128 + ((pos ^ (row & 7)) << 3)] = kreg[i];
        int d = gidx >> 3, vpos = gidx & 7;
        *(us8*)&Vts[d * 64 + ((vpos ^ (d & 7)) << 3)] = vreg[i];
      }
    }
    __syncthreads();   // writes visible to all waves
  }

  // write partials (m in log2 units, l = row-sum from accS)
#pragma unroll
  for (int j3 = 0; j3 < 4; ++j3) {
    int row = w * 16 + fq * 4 + j3;
#pragma unroll
    for (int n = 0; n < 8; ++n)
      accO[row * 128 + n * 16 + fr] = acc[n][j3];
    if (fr == 0) { mlO[row] = mrow[j3]; mlO[64 + row] = accS[j3]; }
  }
}

// ---------------- combine split-K partials -> yb bf16 (exp2-domain m) ----------------
__global__ __launch_bounds__(256)
void attn_combine(const float* __restrict__ accG, const float* __restrict__ mlG,
                  unsigned short* __restrict__ yb) {
  const int j = blockIdx.x;
  const int qb = j >> 4, h = j & 15;
  const float* a0 = accG + (long)(j * 2 + 0) * 8192;
  const float* a1 = accG + (long)(j * 2 + 1) * 8192;
  const float* ml0 = mlG + (j * 2 + 0) * 128;
  const float* ml1 = mlG + (j * 2 + 1) * 128;
  const int tid = threadIdx.x;
#pragma unroll
  for (int e = 0; e < 8; ++e) {
    int idx = e * 256 + tid;            // 0..2047, covers [64][32] f32x4 slots
    int row = idx >> 5;
    int c4  = (idx & 31) * 4;
    float m0 = ml0[row], l0 = ml0[64 + row];
    float m1 = ml1[row], l1 = ml1[64 + row];
    float m  = fmaxf(m0, m1);
    float w0 = exp2f(m0 - m), w1 = exp2f(m1 - m);
    float inv = 1.0f / (l0 * w0 + l1 * w1);
    f32x4 A = *(const f32x4*)(a0 + row * 128 + c4);
    f32x4 B = *(const f32x4*)(a1 + row * 128 + c4);
    us4 o;
#pragma unroll
    for (int q = 0; q < 4; ++q)
      o[q] = f2bf((A[q] * w0 + B[q] * w1) * inv);
    *(us4*)(yb + (long)(qb * 64 + row) * HS + h * 128 + c4) = o;
  }
}

// ---------------- launch ----------------
extern "C" void kernel_launch(void* const* d_in, const int* in_sizes, int n_in,
                              void* d_out, int out_size, void* d_ws, size_t ws_size,
                              hipStream_t stream) {
  const float* x    = (const float*)d_in[0];
  const float* Wqkv = (const float*)d_in[1];
  const float* Wo_w = (const float*)d_in[2];
  const float* Wo_b = (const float*)d_in[3];
  float* out = (float*)d_out;
  char* ws = (char*)d_ws;

  unsigned short* xbf  = (unsigned short*)(ws + 0L);          //  8.0 MB
  unsigned short* wqbf = (unsigned short*)(ws + 8388608L);    // 24.0 MB
  unsigned short* wobf = (unsigned short*)(ws + 33554432L);   //  8.0 MB
  unsigned short* qkv  = (unsigned short*)(ws + 41943040L);   // 24.0 MB (bf16 now)
  unsigned short* qb   = (unsigned short*)(ws + 92274688L);   //  8.0 MB
  unsigned short* kb   = (unsigned short*)(ws + 100663296L);  //  8.0 MB
  unsigned short* vt   = (unsigned short*)(ws + 109051904L);  //  8.0 MB
  unsigned short* yb   = (unsigned short*)(ws + 117440512L);  //  8.0 MB
  float*          cosd = (float*)         (ws + 125829120L);  //  0.5 MB
  float*          sind = (float*)         (ws + 126353408L);  //  0.5 MB
  // overlays (dead by the time attn runs): acc partials over xbf+wqbf, m/l over qkv
  float*          accG = (float*)         (ws + 0L);          // 32.0 MB (1024 x 64 x 128 f32)
  float*          mlG  = (float*)         (ws + 41943040L);   //  0.5 MB (1024 x 128 f32)

  cast_bf16_kernel<<<dim3(4194304 / 8 / 256), 256, 0, stream>>>(x, xbf, 4194304);
  cast_bf16_kernel<<<dim3(12582912 / 8 / 256), 256, 0, stream>>>(Wqkv, wqbf, 12582912);
  cast_bf16_kernel<<<dim3(4194304 / 8 / 256), 256, 0, stream>>>(Wo_w, wobf, 4194304);
  rope_table_kernel<<<dim3(512), 256, 0, stream>>>(cosd, sind);

  gemm_bt<0, 128, 1><<<dim3(QKVN / 128, T_SEQ / 128), 256, 0, stream>>>(xbf, wqbf, (void*)qkv,
                                                                        nullptr, T_SEQ, QKVN, HS);
  normrope_qk<<<dim3(1024), 256, 0, stream>>>(qkv, cosd, sind, qb, kb);
  v_transpose<<<dim3(T_SEQ / 64, NH), 256, 0, stream>>>(qkv, vt);
  attn_kernel<<<dim3(1024), 256, 0, stream>>>(qb, kb, vt, accG, mlG);
  attn_combine<<<dim3(512), 256, 0, stream>>>(accG, mlG, yb);
  gemm_bt<1, 64, 0><<<dim3(HS / 64, T_SEQ / 128), 256, 0, stream>>>(yb, wobf, (void*)out,
                                                                    Wo_b, T_SEQ, HS, HS);
}